// Round 10
// baseline (3580.349 us; speedup 1.0000x reference)
//
#include <hip/hip_runtime.h>
#include <hip/hip_bf16.h>
#include <stdint.h>

// ---------------------------------------------------------------------------
// 2-layer LSTM (B=256, T=1024, H=256), persistent clusters, self-paced
// dataflow. R8-proven protocol, critical path shortened (R10).
//
// R9 post-mortem: XCD-local exchange crashed 3/3 (likely: CU-scope store acks
// don't imply L2 visibility -> flag stuck in WC buffer -> consumer spin ->
// timeout; and gfx950 SC scopes are {CU,SE,Agent,System} - no XCD scope).
// Abandoned. R10 = R8 + three safe cuts:
//  A) out-reduce moved AFTER publish+flag (was mid-step in 1-of-8 WGs; the
//     cluster advances at max-of-8, so its ~1300cy ldf_coh gated EVERY step;
//     post-flag it's absorbed by the next poll wait).
//  B) per-wave seq flags: flag line dwords 0-3 = per-wave seq. Each wave
//     drains ITS OWN stores (vmcnt is per-wave - R4 lesson) then lane0
//     publishes its seq; no post-drain barrier. Consumer's existing x4 load
//     now checks 4 seqs per line. Same thresholds as R8.
//  C) L1 stages h1(t-1) (flag almost always already set) BEFORE polling the
//     fresh h0(t) flag - overlaps one stage latency with detect wait.
// op(t) freshness for the reduce: L1 seq>=t+1 => step-t drain done => op(t)
// at IC (op stored before that drain). Same argument as R8, unchanged.
// ---------------------------------------------------------------------------

#define TT   1024
#define NC   16
#define MR   16

typedef __attribute__((ext_vector_type(8))) short  bfrag;
typedef __attribute__((ext_vector_type(4))) float  ffrag;
typedef __attribute__((ext_vector_type(4))) int    ifrag;

__device__ __forceinline__ float sigf(float v){ return 1.f/(1.f+__expf(-v)); }
__device__ __forceinline__ float tanhfast(float v){
    v = fminf(fmaxf(v,-15.f),15.f);
    float e = __expf(2.f*v);
    return (e-1.f)/(e+1.f);
}
// Device-coherent publishes (R3/R8-proven visibility protocol).
__device__ __forceinline__ void st32(uint32_t* p, uint32_t v){
    __hip_atomic_store(p, v, __ATOMIC_RELAXED, __HIP_MEMORY_SCOPE_AGENT);
}
__device__ __forceinline__ void st64(unsigned long long* p, unsigned long long v){
    __hip_atomic_store(p, v, __ATOMIC_RELAXED, __HIP_MEMORY_SCOPE_AGENT);
}
__device__ __forceinline__ void stf(float* p, float v){
    __hip_atomic_store(p, v, __ATOMIC_RELAXED, __HIP_MEMORY_SCOPE_AGENT);
}
__device__ __forceinline__ float ldf_coh(const float* p){
    float v;
    __asm__ volatile("global_load_dword %0, %1, off sc0 sc1\n\ts_waitcnt vmcnt(0)"
                     : "=v"(v) : "v"(p) : "memory");
    return v;
}
// Per-wave release drain (vmcnt is per-wave).
__device__ __forceinline__ void drain_vmem(){
    __asm__ volatile("s_waitcnt vmcnt(0)" ::: "memory");
}

// Poll 4 flag lines (each: 4 per-wave seqs in dwords 0-3), parallel x4 loads.
// a,b = L0 producers (all 4 seqs >= tgtA); c,d = L1 producers (>= tgtB).
__device__ __forceinline__ void wave_poll4(const int* fa, const int* fb,
                                           const int* fc, const int* fd,
                                           int tgtA, int tgtB){
    for (;;) {
        ifrag A, B, C, D;
        __asm__ volatile(
            "global_load_dwordx4 %0, %4, off sc0 sc1\n\t"
            "global_load_dwordx4 %1, %5, off sc0 sc1\n\t"
            "global_load_dwordx4 %2, %6, off sc0 sc1\n\t"
            "global_load_dwordx4 %3, %7, off sc0 sc1\n\t"
            "s_waitcnt vmcnt(0)"
            : "=&v"(A), "=&v"(B), "=&v"(C), "=&v"(D)
            : "v"(fa), "v"(fb), "v"(fc), "v"(fd) : "memory");
        if (A[0] >= tgtA && A[1] >= tgtA && A[2] >= tgtA && A[3] >= tgtA &&
            B[0] >= tgtA && B[1] >= tgtA && B[2] >= tgtA && B[3] >= tgtA &&
            C[0] >= tgtB && C[1] >= tgtB && C[2] >= tgtB && C[3] >= tgtB &&
            D[0] >= tgtB && D[1] >= tgtB && D[2] >= tgtB && D[3] >= tgtB) break;
    }
}
// Poll 2 flag lines.
__device__ __forceinline__ void wave_poll2(const int* fa, const int* fb, int tgt){
    for (;;) {
        ifrag A, B;
        __asm__ volatile(
            "global_load_dwordx4 %0, %2, off sc0 sc1\n\t"
            "global_load_dwordx4 %1, %3, off sc0 sc1\n\t"
            "s_waitcnt vmcnt(0)"
            : "=&v"(A), "=&v"(B)
            : "v"(fa), "v"(fb) : "memory");
        if (A[0] >= tgt && A[1] >= tgt && A[2] >= tgt && A[3] >= tgt &&
            B[0] >= tgt && B[1] >= tgt && B[2] >= tgt && B[3] >= tgt) break;
    }
}

// Direct-to-LDS stage of one 16x32 bf16 A-tile from a per-producer 1KB block.
__device__ __forceinline__ void stage_tile(uint32_t* ldsbase, const uint32_t* hblocks,
                                           int kt, int lane){
    const uint32_t* g = hblocks + (kt << 8) + ((lane & 15) << 4) + ((lane >> 4) << 2);
    uint32_t* l = ldsbase + (kt << 8);
    __builtin_amdgcn_global_load_lds(
        (const __attribute__((address_space(1))) uint32_t*)(uintptr_t)g,
        (__attribute__((address_space(3))) uint32_t*)(uint32_t)(uintptr_t)l,
        16, 0, 0x11);
}

__global__ void __launch_bounds__(256, 1)
lstm_kernel(const float* __restrict__ x,
            const float* __restrict__ Wih0, const float* __restrict__ Whh0,
            const float* __restrict__ bih0, const float* __restrict__ bhh0,
            const float* __restrict__ Wih1, const float* __restrict__ Whh1,
            const float* __restrict__ bih1, const float* __restrict__ bhh1,
            const float* __restrict__ Wlin, const float* __restrict__ blin,
            float* __restrict__ out, char* __restrict__ ws)
{
    const int tid = threadIdx.x;
    const int wg  = blockIdx.x;
    const int c   = wg >> 4;
    const int j   = wg & 15;
    const bool isL0 = (j < 8);
    const int  u0   = (isL0 ? j : (j - 8)) * 32;

    // flags: 16 clusters x 16 WGs x 128B private lines; dwords 0-3 = wave seqs
    int* flagbase = (int*)(ws + c * 4096);
    // h: [4 slots][NC][8 producers][16 rows][32 units bf16] = 512 KB each
    uint32_t* h0w = (uint32_t*)(ws + 65536);
    uint32_t* h1w = h0w + 4 * NC * 8 * 256;
    float*    op  = (float*)(h1w + 4 * NC * 8 * 256);    // [4][NC][8][16] fp32

    // ---- LDS carve ----
    __shared__ __attribute__((aligned(16))) char S[157056];
    __hip_bfloat16* Wt   = (__hip_bfloat16*)S;           // L0: Whh0; L1: Wih1 (tiled)
    __hip_bfloat16* Wt2  = (__hip_bfloat16*)(S + 65536); // L1: Whh1 (tiled)
    float*          xs   = (float*)(S + 65536);          // L0: x fp32 (aliases Wt2)
    uint32_t*       hs0  = (uint32_t*)(S + 131072);
    uint32_t*       hs1  = (uint32_t*)(S + 139264);
    float*          gbuf = (float*)(S + 147456);         // [16][132]
    float*          biasS= (float*)(S + 155904);
    float*          wxS  = (float*)(S + 156416);
    float*          sblin= (float*)(S + 156928);

    // fragment geometry (needed early for per-wave init publishes)
    const int lane = tid & 63, wave = tid >> 6;
    const int nt0 = wave * 2, nt1 = wave * 2 + 1;
    const int drow = (lane >> 4) * 4, dcol = lane & 15;
    const int em = tid >> 4, up = tid & 15;
    uint32_t* myflagline = (uint32_t*)(flagbase + j * 32);
    const int* fL0a = flagbase + (wave)      * 32;
    const int* fL0b = flagbase + (wave + 4)  * 32;
    const int* fL1a = flagbase + (8 + wave)  * 32;
    const int* fL1b = flagbase + (12 + wave) * 32;

    // ---- one-time init ----
    {
        const float* Wsrc = isL0 ? Whh0 : Wih1;
        for (int i = tid; i < 128 * 256; i += 256) {
            int n = i >> 8, k = i & 255;
            int r = (n >> 5) * 256 + u0 + (n & 31);
            int ln = (n & 15) | (((k >> 3) & 3) << 4);
            int toff = ((n >> 4) * 8 + (k >> 5)) * 1024 + ln * 16 + (k & 7) * 2;
            *(__hip_bfloat16*)((char*)Wt + toff) = __float2bfloat16(Wsrc[r * 256 + k]);
            if (!isL0)
                *(__hip_bfloat16*)((char*)Wt2 + toff) = __float2bfloat16(Whh1[r * 256 + k]);
        }
        if (isL0) {
            for (int i = tid; i < 16 * 1024; i += 256)
                xs[i] = x[(c * 16 + (i >> 10)) * TT + (i & 1023)];
        }
        if (tid < 128) {
            int r = (tid >> 5) * 256 + u0 + (tid & 31);
            if (isL0) { biasS[tid] = bih0[r] + bhh0[r]; wxS[tid] = Wih0[r]; }
            else      { biasS[tid] = bih1[r] + bhh1[r]; if (tid < 32) wxS[tid] = Wlin[u0 + tid]; }
        }
        if (tid == 0) sblin[0] = blin[0];
        // zero h(-1) = slot 3: thread tid zeroes dword tid of MY block.
        // Wave w's dwords = rows 4w..4w+3 — exactly the rows wave w owns, so
        // a per-wave drain + per-wave seq=0 is a sound release.
        {
            uint32_t* z = isL0 ? (h0w + ((3 * NC + c) * 8 + j) * 256)
                               : (h1w + ((3 * NC + c) * 8 + (j - 8)) * 256);
            st32(z + tid, 0u);
        }
        drain_vmem();
        if (lane == 0) st32(myflagline + wave, 0u);      // per-wave seq = 0
    }

    float c0a = 0.f, c0b = 0.f;

    for (int t = 0; t < TT; ++t) {
        if (isL0) {
            // data: h0(t-1) [L0 seqs >= t]; overwrite-safety [L1 seqs >= t-2]
            wave_poll4(fL0a, fL0b, fL1a, fL1b, t, t - 2);
            const uint32_t* src = h0w + (((t + 3) & 3) * NC + c) * 8 * 256;  // h0(t-1)
            stage_tile(hs0, src, wave, lane);
            stage_tile(hs0, src, wave + 4, lane);
            __syncthreads();

            ffrag a0 = {0.f,0.f,0.f,0.f}, a1 = {0.f,0.f,0.f,0.f};
            #pragma unroll
            for (int kt = 0; kt < 8; ++kt) {
                bfrag av = *(const bfrag*)((const char*)hs0 + kt * 1024 + lane * 16);
                bfrag b0 = *(const bfrag*)((const char*)Wt + (nt0 * 8 + kt) * 1024 + lane * 16);
                bfrag b1 = *(const bfrag*)((const char*)Wt + (nt1 * 8 + kt) * 1024 + lane * 16);
                a0 = __builtin_amdgcn_mfma_f32_16x16x32_bf16(av, b0, a0, 0, 0, 0);
                a1 = __builtin_amdgcn_mfma_f32_16x16x32_bf16(av, b1, a1, 0, 0, 0);
            }
            #pragma unroll
            for (int i = 0; i < 4; ++i) {
                gbuf[(drow + i) * 132 + nt0 * 16 + dcol] = a0[i];
                gbuf[(drow + i) * 132 + nt1 * 16 + dcol] = a1[i];
            }
            __syncthreads();

            float2 g_i = *(float2*)(gbuf + em * 132 +      2 * up);
            float2 g_f = *(float2*)(gbuf + em * 132 + 32 + 2 * up);
            float2 g_g = *(float2*)(gbuf + em * 132 + 64 + 2 * up);
            float2 g_o = *(float2*)(gbuf + em * 132 + 96 + 2 * up);
            float xv = xs[em * 1024 + t];
            float i0 = g_i.x + xv * wxS[     2*up  ] + biasS[     2*up  ];
            float i1 = g_i.y + xv * wxS[     2*up+1] + biasS[     2*up+1];
            float f0 = g_f.x + xv * wxS[32 + 2*up  ] + biasS[32 + 2*up  ];
            float f1 = g_f.y + xv * wxS[32 + 2*up+1] + biasS[32 + 2*up+1];
            float gg0 = g_g.x + xv * wxS[64 + 2*up  ] + biasS[64 + 2*up  ];
            float gg1 = g_g.y + xv * wxS[64 + 2*up+1] + biasS[64 + 2*up+1];
            float o0 = g_o.x + xv * wxS[96 + 2*up  ] + biasS[96 + 2*up  ];
            float o1 = g_o.y + xv * wxS[96 + 2*up+1] + biasS[96 + 2*up+1];
            c0a = sigf(f0) * c0a + sigf(i0) * tanhfast(gg0);
            c0b = sigf(f1) * c0b + sigf(i1) * tanhfast(gg1);
            float hn0 = sigf(o0) * tanhfast(c0a);
            float hn1 = sigf(o1) * tanhfast(c0b);
            __hip_bfloat16 hb0 = __float2bfloat16(hn0), hb1 = __float2bfloat16(hn1);
            uint32_t pk = ((uint32_t)(*(uint16_t*)&hb1) << 16) | (uint32_t)(*(uint16_t*)&hb0);
            uint32_t nb = __shfl_down(pk, 1);
            if ((up & 1) == 0) {
                unsigned long long v = (unsigned long long)pk |
                                       ((unsigned long long)nb << 32);
                st64((unsigned long long*)
                     (h0w + (((t & 3) * NC + c) * 8 + j) * 256 + em * 16 + up), v);
            }
            // per-wave release: my rows ack'd at IC, then my seq (B).
            drain_vmem();
            if (lane == 0) st32(myflagline + wave, (uint32_t)(t + 1));

            // out-reduce column t-3 AFTER the flag (A): off the gating path.
            // op(t-3) valid: this step's poll saw L1 seqs >= t-2 => L1's step
            // t-2 drain done => op(t-3) (stored before that drain) at IC.
            if (t >= 3 && j == ((t - 3) & 7) && tid < 128) {
                int m = tid >> 3, jj = tid & 7;
                float v = ldf_coh(&op[(((t - 3) & 3) * NC + c) * 128 + jj * 16 + m]);
                v += __shfl_down(v, 4, 8);
                v += __shfl_down(v, 2, 8);
                v += __shfl_down(v, 1, 8);
                if (jj == 0) out[(c * 16 + m) * TT + (t - 3)] = v + sblin[0];
            }
        } else {
            // (C) stage the stale-by-one h1(t-1) first (flag usually set),
            // then poll/stage the fresh h0(t) — overlaps one stage latency.
            wave_poll2(fL1a, fL1b, t);                                   // h1(t-1)
            const uint32_t* s1 = h1w + (((t + 3) & 3) * NC + c) * 8 * 256;
            stage_tile(hs1, s1, wave, lane);
            stage_tile(hs1, s1, wave + 4, lane);
            wave_poll2(fL0a, fL0b, t + 1);                               // h0(t)
            const uint32_t* s0 = h0w + ((t & 3) * NC + c) * 8 * 256;
            stage_tile(hs0, s0, wave, lane);
            stage_tile(hs0, s0, wave + 4, lane);
            __syncthreads();

            ffrag a0 = {0.f,0.f,0.f,0.f}, a1 = {0.f,0.f,0.f,0.f};
            #pragma unroll
            for (int kt = 0; kt < 8; ++kt) {       // h0(t) @ Wih1
                bfrag av = *(const bfrag*)((const char*)hs0 + kt * 1024 + lane * 16);
                bfrag b0 = *(const bfrag*)((const char*)Wt + (nt0 * 8 + kt) * 1024 + lane * 16);
                bfrag b1 = *(const bfrag*)((const char*)Wt + (nt1 * 8 + kt) * 1024 + lane * 16);
                a0 = __builtin_amdgcn_mfma_f32_16x16x32_bf16(av, b0, a0, 0, 0, 0);
                a1 = __builtin_amdgcn_mfma_f32_16x16x32_bf16(av, b1, a1, 0, 0, 0);
            }
            #pragma unroll
            for (int kt = 0; kt < 8; ++kt) {       // += h1(t-1) @ Whh1
                bfrag av = *(const bfrag*)((const char*)hs1 + kt * 1024 + lane * 16);
                bfrag b0 = *(const bfrag*)((const char*)Wt2 + (nt0 * 8 + kt) * 1024 + lane * 16);
                bfrag b1 = *(const bfrag*)((const char*)Wt2 + (nt1 * 8 + kt) * 1024 + lane * 16);
                a0 = __builtin_amdgcn_mfma_f32_16x16x32_bf16(av, b0, a0, 0, 0, 0);
                a1 = __builtin_amdgcn_mfma_f32_16x16x32_bf16(av, b1, a1, 0, 0, 0);
            }
            #pragma unroll
            for (int i = 0; i < 4; ++i) {
                gbuf[(drow + i) * 132 + nt0 * 16 + dcol] = a0[i];
                gbuf[(drow + i) * 132 + nt1 * 16 + dcol] = a1[i];
            }
            __syncthreads();

            float2 g_i = *(float2*)(gbuf + em * 132 +      2 * up);
            float2 g_f = *(float2*)(gbuf + em * 132 + 32 + 2 * up);
            float2 g_g = *(float2*)(gbuf + em * 132 + 64 + 2 * up);
            float2 g_o = *(float2*)(gbuf + em * 132 + 96 + 2 * up);
            float i0 = g_i.x + biasS[     2*up  ], i1 = g_i.y + biasS[     2*up+1];
            float f0 = g_f.x + biasS[32 + 2*up  ], f1 = g_f.y + biasS[32 + 2*up+1];
            float gg0 = g_g.x + biasS[64 + 2*up ], gg1 = g_g.y + biasS[64 + 2*up+1];
            float o0 = g_o.x + biasS[96 + 2*up  ], o1 = g_o.y + biasS[96 + 2*up+1];
            c0a = sigf(f0) * c0a + sigf(i0) * tanhfast(gg0);
            c0b = sigf(f1) * c0b + sigf(i1) * tanhfast(gg1);
            float hn0 = sigf(o0) * tanhfast(c0a);
            float hn1 = sigf(o1) * tanhfast(c0b);
            __hip_bfloat16 hb0 = __float2bfloat16(hn0), hb1 = __float2bfloat16(hn1);
            uint32_t pk = ((uint32_t)(*(uint16_t*)&hb1) << 16) | (uint32_t)(*(uint16_t*)&hb0);
            uint32_t nb = __shfl_down(pk, 1);
            if ((up & 1) == 0) {
                unsigned long long v = (unsigned long long)pk |
                                       ((unsigned long long)nb << 32);
                st64((unsigned long long*)
                     (h1w + (((t & 3) * NC + c) * 8 + (j - 8)) * 256 + em * 16 + up), v);
            }
            // out partial for column t (fp32), stored BEFORE the drain so the
            // per-wave seq t+1 also certifies op(t).
            float pv = hn0 * wxS[2 * up] + hn1 * wxS[2 * up + 1];
            pv += __shfl_down(pv, 8, 16);
            pv += __shfl_down(pv, 4, 16);
            pv += __shfl_down(pv, 2, 16);
            pv += __shfl_down(pv, 1, 16);
            if (up == 0)
                stf(&op[((t & 3) * NC + c) * 128 + (j - 8) * 16 + em], pv);
            drain_vmem();
            if (lane == 0) st32(myflagline + wave, (uint32_t)(t + 1));
        }
    }

    // tail: columns TT-3..TT-1 by L0 WGs 5,6,7. L1 seq >= TT => step TT-1
    // drain done => op(TT-1) at IC (op stored before that drain).
    if (isL0 && j >= 5) {
        wave_poll2(fL1a, fL1b, TT);
        __syncthreads();
        int col = TT - 8 + j;            // 1021,1022,1023
        if (tid < 128) {
            int m = tid >> 3, jj = tid & 7;
            float v = ldf_coh(&op[((col & 3) * NC + c) * 128 + jj * 16 + m]);
            v += __shfl_down(v, 4, 8);
            v += __shfl_down(v, 2, 8);
            v += __shfl_down(v, 1, 8);
            if (jj == 0) out[(c * 16 + m) * TT + col] = v + sblin[0];
        }
    }
}

extern "C" void kernel_launch(void* const* d_in, const int* in_sizes, int n_in,
                              void* d_out, int out_size, void* d_ws, size_t ws_size,
                              hipStream_t stream)
{
    const float* x    = (const float*)d_in[0];
    const float* Wih0 = (const float*)d_in[1];
    const float* Whh0 = (const float*)d_in[2];
    const float* bih0 = (const float*)d_in[3];
    const float* bhh0 = (const float*)d_in[4];
    const float* Wih1 = (const float*)d_in[5];
    const float* Whh1 = (const float*)d_in[6];
    const float* bih1 = (const float*)d_in[7];
    const float* bhh1 = (const float*)d_in[8];
    const float* Wlin = (const float*)d_in[9];
    const float* blin = (const float*)d_in[10];
    float* out = (float*)d_out;
    char* ws   = (char*)d_ws;

    // 256 blocks x 256 threads, 1 block/CU -> all co-resident (spin-safe).
    lstm_kernel<<<dim3(256), dim3(256), 0, stream>>>(
        x, Wih0, Whh0, bih0, bhh0, Wih1, Whh1, bih1, bhh1, Wlin, blin, out, ws);
}